// Round 1
// baseline (1061.493 us; speedup 1.0000x reference)
//
#include <hip/hip_runtime.h>
#include <math.h>

#define D_VOCAB 50257
#define D_MODEL 768

// Phase 1: flat float4 scan of the one-hot tokens array. When a lane sees a
// nonzero component, it resolves (row, col) and records col in idx[row].
// Exactly one element per row is nonzero, so every idx entry gets written
// every call (d_ws is re-poisoned to 0xAA before each timed launch).
__global__ void find_indices(const float4* __restrict__ tok4, unsigned n4,
                             int* __restrict__ idx) {
    unsigned i = blockIdx.x * blockDim.x + threadIdx.x;
    unsigned stride = gridDim.x * blockDim.x;
    for (; i < n4; i += stride) {
        float4 v = tok4[i];
        if (v.x != 0.0f || v.y != 0.0f || v.z != 0.0f || v.w != 0.0f) {
            float vals[4] = {v.x, v.y, v.z, v.w};
            unsigned base = i * 4u;
            #pragma unroll
            for (int c = 0; c < 4; ++c) {
                if (vals[c] != 0.0f) {
                    unsigned flat = base + (unsigned)c;
                    unsigned row = flat / D_VOCAB;      // magic-mul division
                    unsigned col = flat - row * D_VOCAB;
                    idx[row] = (int)col;
                }
            }
        }
    }
}

// Phase 2: out[row, :] = W[idx[row], :] * sqrt(D_MODEL) + bias.
// One float4 per thread; W row start (v*768 floats = 3072 B) is 16B-aligned.
__global__ void gather_embed(const int* __restrict__ idx,
                             const float4* __restrict__ W4,
                             const float4* __restrict__ b4,
                             float4* __restrict__ out4,
                             unsigned n4out) {
    unsigned i = blockIdx.x * blockDim.x + threadIdx.x;
    if (i >= n4out) return;
    const float scale = sqrtf((float)D_MODEL);  // constant-folded
    const unsigned DM4 = D_MODEL / 4;
    unsigned row = i / DM4;
    unsigned d4 = i - row * DM4;
    unsigned v = (unsigned)idx[row];
    float4 w = W4[v * DM4 + d4];
    float4 b = b4[d4];
    float4 o;
    o.x = w.x * scale + b.x;
    o.y = w.y * scale + b.y;
    o.z = w.z * scale + b.z;
    o.w = w.w * scale + b.w;
    out4[i] = o;
}

extern "C" void kernel_launch(void* const* d_in, const int* in_sizes, int n_in,
                              void* d_out, int out_size, void* d_ws, size_t ws_size,
                              hipStream_t stream) {
    const float* tokens = (const float*)d_in[0];        // [B*P, V] fp32 one-hot
    const float* weights = (const float*)d_in[1];       // [V, D] fp32
    const float* bias = (const float*)d_in[2];          // [D] fp32
    float* out = (float*)d_out;                          // [B*P, D] fp32
    int* idx = (int*)d_ws;                               // [B*P] int32 scratch

    unsigned n_tok = (unsigned)in_sizes[0];
    unsigned n4 = n_tok / 4u;                            // 205,852,672 / 4 — exact

    // Phase 1: saturate HBM with the scan. 8192 blocks x 256 thr, grid-stride.
    unsigned blocks1 = 8192;
    find_indices<<<blocks1, 256, 0, stream>>>((const float4*)tokens, n4, idx);

    // Phase 2: one float4 per thread over the output.
    unsigned n4out = (unsigned)out_size / 4u;            // 786,432
    unsigned blocks2 = (n4out + 255u) / 256u;
    gather_embed<<<blocks2, 256, 0, stream>>>(idx, (const float4*)weights,
                                              (const float4*)bias,
                                              (float4*)out, n4out);
}